// Round 1
// baseline (2220.019 us; speedup 1.0000x reference)
//
#include <hip/hip_runtime.h>
#include <math.h>

#define NN 4003            // label nodes
#define UU 2048            // unify nodes
#define NORMC (-8.7079796f)   // -log(4003+2048)

// ---------------- concat: feats = [datasets ; unlable]  [NN,256] ----------------
__global__ void concat_kernel(const float* __restrict__ a, const float* __restrict__ b,
                              float* __restrict__ out) {
    int i = blockIdx.x * blockDim.x + threadIdx.x;
    const int tot4 = NN * 256 / 4;              // 256192 float4s
    if (i >= tot4) return;
    const float4* a4 = (const float4*)a;
    const float4* b4 = (const float4*)b;
    float4* o4 = (float4*)out;
    o4[i] = (i < 256000) ? a4[i] : b4[i - 256000];
}

// ---------------- transpose S[NN][UU] -> ST[UU][NN] ----------------
__global__ void transpose_kernel(const float* __restrict__ in, float* __restrict__ out) {
    __shared__ float tile[32][33];
    int x = blockIdx.x * 32 + threadIdx.x;       // UU dim (always < 2048)
    int y0 = blockIdx.y * 32;                    // NN dim
    for (int r = threadIdx.y; r < 32; r += 8) {
        int y = y0 + r;
        tile[r][threadIdx.x] = (y < NN) ? in[(size_t)y * UU + x] : 0.0f;
    }
    __syncthreads();
    int oc = y0 + threadIdx.x;                   // col in out (NN dim)
    for (int r = threadIdx.y; r < 32; r += 8) {
        int orow = blockIdx.x * 32 + r;
        if (oc < NN) out[(size_t)orow * NN + oc] = tile[threadIdx.x][r];
    }
}

// ---------------- row logsumexp: outv[r] = NORMC - lse_j(S[r][j] + addv[j]) -----
__global__ __launch_bounds__(256) void lse_rows(const float* __restrict__ S,
                                                const float* __restrict__ addv,
                                                float* __restrict__ outv, int C) {
    int r = blockIdx.x;
    const float* row = S + (size_t)r * C;
    float m = -INFINITY, s = 0.0f;
    for (int j = threadIdx.x; j < C; j += 256) {
        float x = row[j] + addv[j];
        float nm = fmaxf(m, x);
        s = s * __expf(m - nm) + __expf(x - nm);
        m = nm;
    }
    #pragma unroll
    for (int off = 1; off < 64; off <<= 1) {
        float om = __shfl_xor(m, off, 64);
        float os = __shfl_xor(s, off, 64);
        float nm = fmaxf(m, om);
        s = s * __expf(m - nm) + os * __expf(om - nm);
        m = nm;
    }
    __shared__ float sm[4], ss[4];
    int w = threadIdx.x >> 6;
    if ((threadIdx.x & 63) == 0) { sm[w] = m; ss[w] = s; }
    __syncthreads();
    if (threadIdx.x == 0) {
        m = sm[0]; s = ss[0];
        #pragma unroll
        for (int i = 1; i < 4; ++i) {
            float om = sm[i], os = ss[i];
            float nm = fmaxf(m, om);
            s = s * __expf(m - nm) + os * __expf(om - nm);
            m = nm;
        }
        outv[r] = NORMC - (m + __logf(s));
    }
}

// ---------------- A = exp(S + u + v - NORMC) ----------------
__global__ void make_A(const float* __restrict__ S, const float* __restrict__ u,
                       const float* __restrict__ v, float* __restrict__ A) {
    int idx = blockIdx.x * 256 + threadIdx.x;    // float4 index
    const int tot4 = NN * UU / 4;                // 2049536
    if (idx >= tot4) return;
    int i = idx >> 9;                            // 512 float4 per row
    int j = (idx & 511) << 2;
    float4 sv = ((const float4*)S)[idx];
    float ui = u[i] - NORMC;
    float4 r;
    r.x = __expf(sv.x + ui + v[j + 0]);
    r.y = __expf(sv.y + ui + v[j + 1]);
    r.z = __expf(sv.z + ui + v[j + 2]);
    r.w = __expf(sv.w + ui + v[j + 3]);
    ((float4*)A)[idx] = r;
}

// ---------------- generic tiled f32 GEMM ----------------
// C[M][N] = act(opA @ B + bias + res),  opA[m][k] = TRANS_A ? A[k*lda+m] : A[m*lda+k]
// ACT: 0 none, 1 relu, 2 tanh
template<int TRANS_A, int ACT, int BIAS, int RES>
__global__ __launch_bounds__(256) void gemm_f32(
        const float* __restrict__ A, const float* __restrict__ B,
        const float* __restrict__ bias, const float* __restrict__ res,
        float* __restrict__ C, int M, int N, int K, int lda) {
    __shared__ __align__(16) float As[16][68];
    __shared__ __align__(16) float Bs[16][68];
    int tid = threadIdx.x;
    int bm = blockIdx.y << 6, bn = blockIdx.x << 6;
    int tx = tid & 15, ty = tid >> 4;
    float acc[4][4] = {};
    for (int k0 = 0; k0 < K; k0 += 16) {
        float4 av = {0.f, 0.f, 0.f, 0.f};
        if (!TRANS_A) {
            int m = tid >> 2, kk = (tid & 3) << 2;
            int gm = bm + m, gk = k0 + kk;
            if (gm < M && gk + 3 < K)
                av = *(const float4*)(A + (size_t)gm * lda + gk);
            As[kk + 0][m] = av.x; As[kk + 1][m] = av.y;
            As[kk + 2][m] = av.z; As[kk + 3][m] = av.w;
        } else {
            int k = tid >> 4, mm = (tid & 15) << 2;
            int gk = k0 + k, gm = bm + mm;
            if (gk < K && gm + 3 < M)
                av = *(const float4*)(A + (size_t)gk * lda + gm);
            *(float4*)&As[k][mm] = av;
        }
        {
            int k = tid >> 4, nn = (tid & 15) << 2;
            int gk = k0 + k, gn = bn + nn;
            float4 bv = {0.f, 0.f, 0.f, 0.f};
            if (gk < K && gn + 3 < N)
                bv = *(const float4*)(B + (size_t)gk * N + gn);
            *(float4*)&Bs[k][nn] = bv;
        }
        __syncthreads();
        #pragma unroll
        for (int k = 0; k < 16; ++k) {
            float4 a = *(const float4*)&As[k][ty << 2];
            float4 b = *(const float4*)&Bs[k][tx << 2];
            float ar[4] = {a.x, a.y, a.z, a.w};
            float br[4] = {b.x, b.y, b.z, b.w};
            #pragma unroll
            for (int i = 0; i < 4; ++i)
                #pragma unroll
                for (int j = 0; j < 4; ++j)
                    acc[i][j] = fmaf(ar[i], br[j], acc[i][j]);
        }
        __syncthreads();
    }
    #pragma unroll
    for (int i = 0; i < 4; ++i) {
        int gm = bm + (ty << 2) + i;
        if (gm >= M) continue;
        #pragma unroll
        for (int j = 0; j < 4; ++j) {
            int gn = bn + (tx << 2) + j;
            if (gn >= N) continue;
            float vv = acc[i][j];
            if (BIAS) vv += bias[gn];
            if (RES)  vv += res[(size_t)gm * N + gn];
            if (ACT == 1) vv = fmaxf(vv, 0.0f);
            if (ACT == 2) vv = tanhf(vv);
            C[(size_t)gm * N + gn] = vv;
        }
    }
}

extern "C" void kernel_launch(void* const* d_in, const int* in_sizes, int n_in,
                              void* d_out, int out_size, void* d_ws, size_t ws_size,
                              hipStream_t stream) {
    const float* dsf = (const float*)d_in[0];
    const float* unl = (const float*)d_in[1];
    const float* S   = (const float*)d_in[2];
    const float* Wb  = (const float*)d_in[3];
    const float* bb  = (const float*)d_in[4];
    const float* gcW[3] = {(const float*)d_in[5], (const float*)d_in[7], (const float*)d_in[9]};
    const float* gcb[3] = {(const float*)d_in[6], (const float*)d_in[8], (const float*)d_in[10]};
    const float* W1 = (const float*)d_in[11];
    const float* b1 = (const float*)d_in[12];
    const float* W2 = (const float*)d_in[13];
    const float* b2 = (const float*)d_in[14];
    float* out = (float*)d_out;

    float* ws = (float*)d_ws;
    size_t o = 0;
    float* ST    = ws + o; o += (size_t)UU * NN;    // reused as A after Sinkhorn
    float* feats = ws + o; o += (size_t)NN * 256;   // reused as hnB after layer 1
    float* x     = ws + o; o += (size_t)NN * 256;
    float* u     = ws + o; o += 4096;
    float* v     = ws + o; o += 2048;
    float* hnA   = ws + o; o += (size_t)NN * 256;
    float* huA   = ws + o; o += (size_t)UU * 256;
    float* huB   = ws + o; o += (size_t)UU * 256;
    float* t_n   = ws + o; o += (size_t)NN * 256;
    float* t_u   = ws + o; o += (size_t)UU * 256;
    float* h1    = ws + o; o += (size_t)UU * 512;
    float* A   = ST;
    float* hnB = feats;

    // 1) feats = concat
    concat_kernel<<<dim3(1001), dim3(256), 0, stream>>>(dsf, unl, feats);
    // 2) x = relu(feats @ Wb + bb)   [NN,256]
    gemm_f32<0, 1, 1, 0><<<dim3(4, 63), dim3(256), 0, stream>>>(
        feats, Wb, bb, nullptr, x, NN, 256, 256, 256);
    // 3) ST = S^T
    transpose_kernel<<<dim3(64, 126), dim3(32, 8), 0, stream>>>(S, ST);
    // 4) v = 0
    hipMemsetAsync(v, 0, UU * sizeof(float), stream);
    // 5) Sinkhorn: 20 iterations (u-update on S rows, v-update on ST rows)
    for (int it = 0; it < 20; ++it) {
        lse_rows<<<dim3(NN), dim3(256), 0, stream>>>(S,  v, u, UU);
        lse_rows<<<dim3(UU), dim3(256), 0, stream>>>(ST, u, v, NN);
    }
    // 6) A = exp(S + u + v - norm)
    make_A<<<dim3((NN * UU / 4 + 255) / 256), dim3(256), 0, stream>>>(S, u, v, A);
    // 7) hu0 = A^T @ x   [UU,256]
    gemm_f32<1, 0, 0, 0><<<dim3(4, 32), dim3(256), 0, stream>>>(
        A, x, nullptr, nullptr, huA, UU, 256, NN, UU);
    // 8) 3 GCN layers
    float* hn_cur = x;   float* hn_nxt = hnA;
    float* hu_cur = huA; float* hu_nxt = huB;
    for (int l = 0; l < 3; ++l) {
        // t_u = hu @ W      [UU,256]
        gemm_f32<0, 0, 0, 0><<<dim3(4, 32), dim3(256), 0, stream>>>(
            hu_cur, gcW[l], nullptr, nullptr, t_u, UU, 256, 256, 256);
        // t_n = hn @ W      [NN,256]
        gemm_f32<0, 0, 0, 0><<<dim3(4, 63), dim3(256), 0, stream>>>(
            hn_cur, gcW[l], nullptr, nullptr, t_n, NN, 256, 256, 256);
        // hn_nxt = tanh(A @ t_u + b + hn_cur)   [NN,256]
        gemm_f32<0, 2, 1, 1><<<dim3(4, 63), dim3(256), 0, stream>>>(
            A, t_u, gcb[l], hn_cur, hn_nxt, NN, 256, UU, UU);
        // hu_nxt = tanh(A^T @ t_n + b + hu_cur) [UU,256]
        gemm_f32<1, 2, 1, 1><<<dim3(4, 32), dim3(256), 0, stream>>>(
            A, t_n, gcb[l], hu_cur, hu_nxt, UU, 256, NN, UU);
        if (l == 0)      { hn_cur = hnA; hn_nxt = hnB; }
        else if (l == 1) { hn_cur = hnB; hn_nxt = hnA; }
        float* tmp = hu_cur; hu_cur = hu_nxt; hu_nxt = tmp;
    }
    // 9) head: out = relu(hu @ W1 + b1) @ W2 + b2
    gemm_f32<0, 1, 1, 0><<<dim3(8, 32), dim3(256), 0, stream>>>(
        hu_cur, W1, b1, nullptr, h1, UU, 512, 256, 256);
    gemm_f32<0, 0, 1, 0><<<dim3(4, 32), dim3(256), 0, stream>>>(
        h1, W2, b2, nullptr, out, UU, 256, 512, 512);
}

// Round 2
// 1018.176 us; speedup vs baseline: 2.1804x; 2.1804x over previous
//
#include <hip/hip_runtime.h>
#include <math.h>

#define NN 4003            // label nodes
#define UU 2048            // unify nodes
#define LDST 4016          // padded leading dim of S^T (float4-aligned rows)
#define NORMC (-8.7079796f)   // -log(4003+2048)
#define PSTR 1048576       // partial-plane stride in floats (= 2048*512 max tile)

// ---------------- concat: feats = [datasets ; unlable]  [NN,256] ----------------
__global__ void concat_kernel(const float* __restrict__ a, const float* __restrict__ b,
                              float* __restrict__ out) {
    int i = blockIdx.x * blockDim.x + threadIdx.x;
    const int tot4 = NN * 256 / 4;              // 256192 float4s
    if (i >= tot4) return;
    const float4* a4 = (const float4*)a;
    const float4* b4 = (const float4*)b;
    float4* o4 = (float4*)out;
    o4[i] = (i < 256000) ? a4[i] : b4[i - 256000];
}

// ---------------- transpose S[NN][UU] -> ST[UU][LDST] ----------------
__global__ void transpose_kernel(const float* __restrict__ in, float* __restrict__ out) {
    __shared__ float tile[32][33];
    int x = blockIdx.x * 32 + threadIdx.x;       // UU dim (always < 2048)
    int y0 = blockIdx.y * 32;                    // NN dim
    for (int r = threadIdx.y; r < 32; r += 8) {
        int y = y0 + r;
        tile[r][threadIdx.x] = (y < NN) ? in[(size_t)y * UU + x] : 0.0f;
    }
    __syncthreads();
    int oc = y0 + threadIdx.x;                   // col in out (NN dim)
    for (int r = threadIdx.y; r < 32; r += 8) {
        int orow = blockIdx.x * 32 + r;
        if (oc < NN) out[(size_t)orow * LDST + oc] = tile[threadIdx.x][r];
    }
}

// ------- row logsumexp: outv[r] = NORMC - lse_j(S[r][j] + addv[j]), float4 -------
__global__ __launch_bounds__(256) void lse_rows(const float* __restrict__ S, int lda,
                                                const float* __restrict__ addv,
                                                float* __restrict__ outv, int C) {
    int r = blockIdx.x;
    const float* row = S + (size_t)r * lda;
    const float4* row4 = (const float4*)row;
    const float4* a4 = (const float4*)addv;
    float m = -INFINITY, s = 0.0f;
    int C4 = C >> 2;
    for (int j = threadIdx.x; j < C4; j += 256) {
        float4 xv = row4[j];
        float4 av = a4[j];
        float x0 = xv.x + av.x, x1 = xv.y + av.y, x2 = xv.z + av.z, x3 = xv.w + av.w;
        float mx = fmaxf(fmaxf(x0, x1), fmaxf(x2, x3));
        float nm = fmaxf(m, mx);
        s = s * __expf(m - nm) + __expf(x0 - nm) + __expf(x1 - nm)
                               + __expf(x2 - nm) + __expf(x3 - nm);
        m = nm;
    }
    int rem = C & 3;
    if ((int)threadIdx.x < rem) {
        int j = (C4 << 2) + threadIdx.x;
        float x = row[j] + addv[j];
        float nm = fmaxf(m, x);
        s = s * __expf(m - nm) + __expf(x - nm);
        m = nm;
    }
    #pragma unroll
    for (int off = 1; off < 64; off <<= 1) {
        float om = __shfl_xor(m, off, 64);
        float os = __shfl_xor(s, off, 64);
        float nm = fmaxf(m, om);
        s = s * __expf(m - nm) + os * __expf(om - nm);
        m = nm;
    }
    __shared__ float sm[4], ss[4];
    int w = threadIdx.x >> 6;
    if ((threadIdx.x & 63) == 0) { sm[w] = m; ss[w] = s; }
    __syncthreads();
    if (threadIdx.x == 0) {
        m = sm[0]; s = ss[0];
        #pragma unroll
        for (int i = 1; i < 4; ++i) {
            float om = sm[i], os = ss[i];
            float nm = fmaxf(m, om);
            s = s * __expf(m - nm) + os * __expf(om - nm);
            m = nm;
        }
        outv[r] = NORMC - (m + __logf(s));
    }
}

// ---------------- A = exp(S + u + v - NORMC) ----------------
__global__ void make_A(const float* __restrict__ S, const float* __restrict__ u,
                       const float* __restrict__ v, float* __restrict__ A) {
    int idx = blockIdx.x * 256 + threadIdx.x;    // float4 index
    const int tot4 = NN * UU / 4;                // 2049536
    if (idx >= tot4) return;
    int i = idx >> 9;                            // 512 float4 per row
    int j = (idx & 511) << 2;
    float4 sv = ((const float4*)S)[idx];
    float ui = u[i] - NORMC;
    float4 r;
    r.x = __expf(sv.x + ui + v[j + 0]);
    r.y = __expf(sv.y + ui + v[j + 1]);
    r.z = __expf(sv.z + ui + v[j + 2]);
    r.w = __expf(sv.w + ui + v[j + 3]);
    ((float4*)A)[idx] = r;
}

// ============ split-K GEMM: partial P[z][m][n] over K-chunk z ============
// opA[m][k] = TRANS_A ? A[k*lda+m] : A[m*lda+k]
template<int TRANS_A>
__global__ __launch_bounds__(256) void gemm_split(
        const float* __restrict__ A, const float* __restrict__ B,
        float* __restrict__ P, int M, int N, int K, int lda, int Kc) {
    __shared__ __align__(16) float As[16][68];
    __shared__ __align__(16) float Bs[16][68];
    int tid = threadIdx.x;
    int bm = blockIdx.y << 6, bn = blockIdx.x << 6;
    int tx = tid & 15, ty = tid >> 4;
    int kb = blockIdx.z * Kc;
    int ke = kb + Kc; if (ke > K) ke = K;
    float acc[4][4] = {};
    for (int k0 = kb; k0 < ke; k0 += 16) {
        float4 av = {0.f, 0.f, 0.f, 0.f};
        if (!TRANS_A) {
            int m = tid >> 2, kk = (tid & 3) << 2;
            int gm = bm + m, gk = k0 + kk;
            if (gm < M && gk + 3 < K)
                av = *(const float4*)(A + (size_t)gm * lda + gk);
            As[kk + 0][m] = av.x; As[kk + 1][m] = av.y;
            As[kk + 2][m] = av.z; As[kk + 3][m] = av.w;
        } else {
            int k = tid >> 4, mm = (tid & 15) << 2;
            int gk = k0 + k, gm = bm + mm;
            if (gk < K && gm + 3 < M)
                av = *(const float4*)(A + (size_t)gk * lda + gm);
            *(float4*)&As[k][mm] = av;
        }
        {
            int k = tid >> 4, nn = (tid & 15) << 2;
            int gk = k0 + k, gn = bn + nn;
            float4 bv = {0.f, 0.f, 0.f, 0.f};
            if (gk < K && gn + 3 < N)
                bv = *(const float4*)(B + (size_t)gk * N + gn);
            *(float4*)&Bs[k][nn] = bv;
        }
        __syncthreads();
        #pragma unroll
        for (int k = 0; k < 16; ++k) {
            float4 a = *(const float4*)&As[k][ty << 2];
            float4 b = *(const float4*)&Bs[k][tx << 2];
            float ar[4] = {a.x, a.y, a.z, a.w};
            float br[4] = {b.x, b.y, b.z, b.w};
            #pragma unroll
            for (int i = 0; i < 4; ++i)
                #pragma unroll
                for (int j = 0; j < 4; ++j)
                    acc[i][j] = fmaf(ar[i], br[j], acc[i][j]);
        }
        __syncthreads();
    }
    float* Pp = P + (size_t)blockIdx.z * PSTR;
    #pragma unroll
    for (int i = 0; i < 4; ++i) {
        int gm = bm + (ty << 2) + i;
        if (gm >= M) continue;
        #pragma unroll
        for (int j = 0; j < 4; ++j) {
            int gn = bn + (tx << 2) + j;
            if (gn < N) Pp[(size_t)gm * N + gn] = acc[i][j];
        }
    }
}

// ---- reduce partials + fused epilogue: C = act(sum_z P[z] + bias + res) ----
template<int ACT, int BIAS, int RES>
__global__ __launch_bounds__(256) void reduce_ep(
        const float* __restrict__ P, const float* __restrict__ bias,
        const float* __restrict__ res, float* __restrict__ C,
        int M, int N, int KS) {
    int t = blockIdx.x * 256 + threadIdx.x;
    int tot4 = (M * N) >> 2;
    if (t >= tot4) return;
    const float4* P4 = (const float4*)P;
    float4 a = P4[t];
    for (int s = 1; s < KS; ++s) {
        float4 b = P4[t + (size_t)s * (PSTR / 4)];
        a.x += b.x; a.y += b.y; a.z += b.z; a.w += b.w;
    }
    int n0 = (t << 2) & (N - 1);   // N is a power of two (256/512)
    if (BIAS) {
        float4 bv = ((const float4*)bias)[n0 >> 2];
        a.x += bv.x; a.y += bv.y; a.z += bv.z; a.w += bv.w;
    }
    if (RES) {
        float4 rv = ((const float4*)res)[t];
        a.x += rv.x; a.y += rv.y; a.z += rv.z; a.w += rv.w;
    }
    if (ACT == 1) {
        a.x = fmaxf(a.x, 0.f); a.y = fmaxf(a.y, 0.f);
        a.z = fmaxf(a.z, 0.f); a.w = fmaxf(a.w, 0.f);
    }
    if (ACT == 2) {
        a.x = tanhf(a.x); a.y = tanhf(a.y); a.z = tanhf(a.z); a.w = tanhf(a.w);
    }
    ((float4*)C)[t] = a;
}

// ---------------- fallback fused GEMM (used only if ws too small) ----------------
template<int TRANS_A, int ACT, int BIAS, int RES>
__global__ __launch_bounds__(256) void gemm_f32(
        const float* __restrict__ A, const float* __restrict__ B,
        const float* __restrict__ bias, const float* __restrict__ res,
        float* __restrict__ C, int M, int N, int K, int lda) {
    __shared__ __align__(16) float As[16][68];
    __shared__ __align__(16) float Bs[16][68];
    int tid = threadIdx.x;
    int bm = blockIdx.y << 6, bn = blockIdx.x << 6;
    int tx = tid & 15, ty = tid >> 4;
    float acc[4][4] = {};
    for (int k0 = 0; k0 < K; k0 += 16) {
        float4 av = {0.f, 0.f, 0.f, 0.f};
        if (!TRANS_A) {
            int m = tid >> 2, kk = (tid & 3) << 2;
            int gm = bm + m, gk = k0 + kk;
            if (gm < M && gk + 3 < K)
                av = *(const float4*)(A + (size_t)gm * lda + gk);
            As[kk + 0][m] = av.x; As[kk + 1][m] = av.y;
            As[kk + 2][m] = av.z; As[kk + 3][m] = av.w;
        } else {
            int k = tid >> 4, mm = (tid & 15) << 2;
            int gk = k0 + k, gm = bm + mm;
            if (gk < K && gm + 3 < M)
                av = *(const float4*)(A + (size_t)gk * lda + gm);
            *(float4*)&As[k][mm] = av;
        }
        {
            int k = tid >> 4, nn = (tid & 15) << 2;
            int gk = k0 + k, gn = bn + nn;
            float4 bv = {0.f, 0.f, 0.f, 0.f};
            if (gk < K && gn + 3 < N)
                bv = *(const float4*)(B + (size_t)gk * N + gn);
            *(float4*)&Bs[k][nn] = bv;
        }
        __syncthreads();
        #pragma unroll
        for (int k = 0; k < 16; ++k) {
            float4 a = *(const float4*)&As[k][ty << 2];
            float4 b = *(const float4*)&Bs[k][tx << 2];
            float ar[4] = {a.x, a.y, a.z, a.w};
            float br[4] = {b.x, b.y, b.z, b.w};
            #pragma unroll
            for (int i = 0; i < 4; ++i)
                #pragma unroll
                for (int j = 0; j < 4; ++j)
                    acc[i][j] = fmaf(ar[i], br[j], acc[i][j]);
        }
        __syncthreads();
    }
    #pragma unroll
    for (int i = 0; i < 4; ++i) {
        int gm = bm + (ty << 2) + i;
        if (gm >= M) continue;
        #pragma unroll
        for (int j = 0; j < 4; ++j) {
            int gn = bn + (tx << 2) + j;
            if (gn >= N) continue;
            float vv = acc[i][j];
            if (BIAS) vv += bias[gn];
            if (RES)  vv += res[(size_t)gm * N + gn];
            if (ACT == 1) vv = fmaxf(vv, 0.0f);
            if (ACT == 2) vv = tanhf(vv);
            C[(size_t)gm * N + gn] = vv;
        }
    }
}

// host-side GEMM dispatcher: split-K path if partial buffer fits, else fused
static void launch_gemm(const float* A, const float* B, const float* bias,
                        const float* res, float* C, int M, int N, int K, int lda,
                        bool transA, int act, bool hasBias, bool hasRes,
                        float* P, int KS, hipStream_t stream) {
    if (P && KS >= 1) {
        int ksg = K / 64; if (ksg < 1) ksg = 1; if (ksg > KS) ksg = KS;
        int Kc = ((K + ksg - 1) / ksg + 15) & ~15;
        dim3 grid((N + 63) / 64, (M + 63) / 64, ksg);
        if (transA) gemm_split<1><<<grid, 256, 0, stream>>>(A, B, P, M, N, K, lda, Kc);
        else        gemm_split<0><<<grid, 256, 0, stream>>>(A, B, P, M, N, K, lda, Kc);
        dim3 g2((((M * N) >> 2) + 255) / 256);
        if (act == 2)      reduce_ep<2, 1, 1><<<g2, 256, 0, stream>>>(P, bias, res, C, M, N, ksg);
        else if (act == 1) reduce_ep<1, 1, 0><<<g2, 256, 0, stream>>>(P, bias, res, C, M, N, ksg);
        else if (hasBias)  reduce_ep<0, 1, 0><<<g2, 256, 0, stream>>>(P, bias, res, C, M, N, ksg);
        else               reduce_ep<0, 0, 0><<<g2, 256, 0, stream>>>(P, bias, res, C, M, N, ksg);
    } else {
        dim3 grid((N + 63) / 64, (M + 63) / 64);
        if (transA) {
            if (act == 2)  gemm_f32<1, 2, 1, 1><<<grid, 256, 0, stream>>>(A, B, bias, res, C, M, N, K, lda);
            else           gemm_f32<1, 0, 0, 0><<<grid, 256, 0, stream>>>(A, B, bias, res, C, M, N, K, lda);
        } else {
            if (act == 2)       gemm_f32<0, 2, 1, 1><<<grid, 256, 0, stream>>>(A, B, bias, res, C, M, N, K, lda);
            else if (act == 1)  gemm_f32<0, 1, 1, 0><<<grid, 256, 0, stream>>>(A, B, bias, res, C, M, N, K, lda);
            else if (hasBias)   gemm_f32<0, 0, 1, 0><<<grid, 256, 0, stream>>>(A, B, bias, res, C, M, N, K, lda);
            else                gemm_f32<0, 0, 0, 0><<<grid, 256, 0, stream>>>(A, B, bias, res, C, M, N, K, lda);
        }
    }
}

extern "C" void kernel_launch(void* const* d_in, const int* in_sizes, int n_in,
                              void* d_out, int out_size, void* d_ws, size_t ws_size,
                              hipStream_t stream) {
    const float* dsf = (const float*)d_in[0];
    const float* unl = (const float*)d_in[1];
    const float* S   = (const float*)d_in[2];
    const float* Wb  = (const float*)d_in[3];
    const float* bb  = (const float*)d_in[4];
    const float* gcW[3] = {(const float*)d_in[5], (const float*)d_in[7], (const float*)d_in[9]};
    const float* gcb[3] = {(const float*)d_in[6], (const float*)d_in[8], (const float*)d_in[10]};
    const float* W1 = (const float*)d_in[11];
    const float* b1 = (const float*)d_in[12];
    const float* W2 = (const float*)d_in[13];
    const float* b2 = (const float*)d_in[14];
    float* out = (float*)d_out;

    float* ws = (float*)d_ws;
    size_t o = 0;
    float* ST    = ws + o; o += (size_t)UU * LDST;  // 8,224,768; reused as A
    float* feats = ws + o; o += (size_t)NN * 256;   // reused as hnB after layer 1
    float* x     = ws + o; o += (size_t)NN * 256;
    float* u     = ws + o; o += 4096;
    float* v     = ws + o; o += 2048;
    float* hnA   = ws + o; o += (size_t)NN * 256;
    float* huA   = ws + o; o += (size_t)UU * 256;
    float* huB   = ws + o; o += (size_t)UU * 256;
    float* t_n   = ws + o; o += (size_t)NN * 256;
    float* t_u   = ws + o; o += (size_t)UU * 256;
    float* h1    = ws + o; o += (size_t)UU * 512;
    float* A   = ST;
    float* hnB = feats;

    // split-K partial planes: as many 1M-float planes as fit (up to 8)
    size_t availf = (ws_size / 4 > o) ? (ws_size / 4 - o) : 0;
    int KS = (int)(availf / PSTR); if (KS > 8) KS = 8;
    float* P = (KS >= 1) ? (ws + o) : nullptr;

    // 1) feats = concat
    concat_kernel<<<dim3(1001), dim3(256), 0, stream>>>(dsf, unl, feats);
    // 2) x = relu(feats @ Wb + bb)   [NN,256]
    launch_gemm(feats, Wb, bb, nullptr, x, NN, 256, 256, 256, false, 1, true, false, P, KS, stream);
    // 3) ST = S^T (padded rows)
    transpose_kernel<<<dim3(64, 126), dim3(32, 8), 0, stream>>>(S, ST);
    // 4) v = 0
    hipMemsetAsync(v, 0, UU * sizeof(float), stream);
    // 5) Sinkhorn: 20 iterations
    for (int it = 0; it < 20; ++it) {
        lse_rows<<<dim3(NN), dim3(256), 0, stream>>>(S,  UU,   v, u, UU);
        lse_rows<<<dim3(UU), dim3(256), 0, stream>>>(ST, LDST, u, v, NN);
    }
    // 6) A = exp(S + u + v - norm)
    make_A<<<dim3((NN * UU / 4 + 255) / 256), dim3(256), 0, stream>>>(S, u, v, A);
    // 7) hu0 = A^T @ x   [UU,256]
    launch_gemm(A, x, nullptr, nullptr, huA, UU, 256, NN, UU, true, 0, false, false, P, KS, stream);
    // 8) 3 GCN layers
    float* hn_cur = x;   float* hn_nxt = hnA;
    float* hu_cur = huA; float* hu_nxt = huB;
    for (int l = 0; l < 3; ++l) {
        launch_gemm(hu_cur, gcW[l], nullptr, nullptr, t_u, UU, 256, 256, 256, false, 0, false, false, P, KS, stream);
        launch_gemm(hn_cur, gcW[l], nullptr, nullptr, t_n, NN, 256, 256, 256, false, 0, false, false, P, KS, stream);
        launch_gemm(A, t_u, gcb[l], hn_cur, hn_nxt, NN, 256, UU, UU, false, 2, true, true, P, KS, stream);
        launch_gemm(A, t_n, gcb[l], hu_cur, hu_nxt, UU, 256, NN, UU, true, 2, true, true, P, KS, stream);
        if (l == 0)      { hn_cur = hnA; hn_nxt = hnB; }
        else if (l == 1) { hn_cur = hnB; hn_nxt = hnA; }
        float* tmp = hu_cur; hu_cur = hu_nxt; hu_nxt = tmp;
    }
    // 9) head: out = relu(hu @ W1 + b1) @ W2 + b2
    launch_gemm(hu_cur, W1, b1, nullptr, h1, UU, 512, 256, 256, false, 1, true, false, P, KS, stream);
    launch_gemm(h1, W2, b2, nullptr, out, UU, 256, 512, 512, false, 0, true, false, P, KS, stream);
}

// Round 3
// 791.796 us; speedup vs baseline: 2.8038x; 1.2859x over previous
//
#include <hip/hip_runtime.h>
#include <math.h>

#define NN 4003            // label nodes
#define UU 2048            // unify nodes
#define KP 4032            // node dim padded to multiple of 64
#define NORMC (-8.7079796f)   // -log(4003+2048)

using bf16x8 = __attribute__((ext_vector_type(8))) short;
using f32x4  = __attribute__((ext_vector_type(4))) float;

__device__ __forceinline__ ushort f2bf(float x) {
    unsigned u = __builtin_bit_cast(unsigned, x);
    u += 0x7fff + ((u >> 16) & 1);          // round-to-nearest-even
    return (ushort)(u >> 16);
}
__device__ __forceinline__ float bf2f(ushort h) {
    unsigned u = ((unsigned)h) << 16;
    return __builtin_bit_cast(float, u);
}
__device__ __forceinline__ void bfsplit(float x, ushort& hi, ushort& lo) {
    hi = f2bf(x);
    lo = f2bf(x - bf2f(hi));
}

// ---------- concat + f32->bf16 hi/lo: feats_bf [NN][256] ----------
__global__ void concat_bf(const float* __restrict__ a, const float* __restrict__ b,
                          ushort* __restrict__ fh, ushort* __restrict__ fl) {
    int i = blockIdx.x * 256 + threadIdx.x;      // float4 index
    const int tot4 = NN * 256 / 4;               // 256192
    if (i >= tot4) return;
    float4 v = (i < 256000) ? ((const float4*)a)[i] : ((const float4*)b)[i - 256000];
    ushort4 hv, lv;
    bfsplit(v.x, hv.x, lv.x); bfsplit(v.y, hv.y, lv.y);
    bfsplit(v.z, hv.z, lv.z); bfsplit(v.w, hv.w, lv.w);
    *(ushort4*)(fh + ((size_t)i << 2)) = hv;
    *(ushort4*)(fl + ((size_t)i << 2)) = lv;
}

// ---------- weight convert: W f32 [K][Nw] -> WT hi/lo bf16 [Nw][K] ----------
__global__ void convW(const float* __restrict__ W, ushort* __restrict__ Th,
                      ushort* __restrict__ Tl, int K, int Nw) {
    __shared__ float tile[32][33];
    int bx = blockIdx.x, by = blockIdx.y;        // bx: Nw tiles, by: K tiles
    int tx = threadIdx.x;
    for (int r = threadIdx.y; r < 32; r += 8)
        tile[r][tx] = W[(size_t)(by * 32 + r) * Nw + bx * 32 + tx];
    __syncthreads();
    for (int r = threadIdx.y; r < 32; r += 8) {
        int n = bx * 32 + r, k = by * 32 + tx;
        ushort hi, lo; bfsplit(tile[tx][r], hi, lo);
        Th[(size_t)n * K + k] = hi;
        Tl[(size_t)n * K + k] = lo;
    }
}

// ---------- transpose S[NN][UU] -> ST f32 [UU][KP] (sinkhorn col pass) ----------
__global__ void transpose_kernel(const float* __restrict__ in, float* __restrict__ out) {
    __shared__ float tile[32][33];
    int x = blockIdx.x * 32 + threadIdx.x;       // UU dim
    int y0 = blockIdx.y * 32;                    // NN dim
    for (int r = threadIdx.y; r < 32; r += 8) {
        int y = y0 + r;
        tile[r][threadIdx.x] = (y < NN) ? in[(size_t)y * UU + x] : 0.0f;
    }
    __syncthreads();
    int oc = y0 + threadIdx.x;
    for (int r = threadIdx.y; r < 32; r += 8) {
        int orow = blockIdx.x * 32 + r;
        out[(size_t)orow * KP + oc] = tile[threadIdx.x][r];
    }
}

// ------- row logsumexp: outv[r] = NORMC - lse_j(S[r][j] + addv[j]) -------
__global__ __launch_bounds__(256) void lse_rows(const float* __restrict__ S, int lda,
                                                const float* __restrict__ addv,
                                                float* __restrict__ outv, int C) {
    int r = blockIdx.x;
    const float* row = S + (size_t)r * lda;
    const float4* row4 = (const float4*)row;
    const float4* a4 = (const float4*)addv;
    float m = -INFINITY, s = 0.0f;
    int C4 = C >> 2;
    for (int j = threadIdx.x; j < C4; j += 256) {
        float4 xv = row4[j];
        float4 av = a4[j];
        float x0 = xv.x + av.x, x1 = xv.y + av.y, x2 = xv.z + av.z, x3 = xv.w + av.w;
        float mx = fmaxf(fmaxf(x0, x1), fmaxf(x2, x3));
        float nm = fmaxf(m, mx);
        s = s * __expf(m - nm) + __expf(x0 - nm) + __expf(x1 - nm)
                               + __expf(x2 - nm) + __expf(x3 - nm);
        m = nm;
    }
    int rem = C & 3;
    if ((int)threadIdx.x < rem) {
        int j = (C4 << 2) + threadIdx.x;
        float x = row[j] + addv[j];
        float nm = fmaxf(m, x);
        s = s * __expf(m - nm) + __expf(x - nm);
        m = nm;
    }
    #pragma unroll
    for (int off = 1; off < 64; off <<= 1) {
        float om = __shfl_xor(m, off, 64);
        float os = __shfl_xor(s, off, 64);
        float nm = fmaxf(m, om);
        s = s * __expf(m - nm) + os * __expf(om - nm);
        m = nm;
    }
    __shared__ float sm[4], ss[4];
    int w = threadIdx.x >> 6;
    if ((threadIdx.x & 63) == 0) { sm[w] = m; ss[w] = s; }
    __syncthreads();
    if (threadIdx.x == 0) {
        m = sm[0]; s = ss[0];
        #pragma unroll
        for (int i = 1; i < 4; ++i) {
            float om = sm[i], os = ss[i];
            float nm = fmaxf(m, om);
            s = s * __expf(m - nm) + os * __expf(om - nm);
            m = nm;
        }
        outv[r] = NORMC - (m + __logf(s));
    }
}

// ---------- A_bf = exp(S + u + v - NORMC) hi/lo, [NN][UU] ----------
__global__ void make_A(const float* __restrict__ S, const float* __restrict__ u,
                       const float* __restrict__ v, ushort* __restrict__ Ah,
                       ushort* __restrict__ Al) {
    int idx = blockIdx.x * 256 + threadIdx.x;    // float4 index
    const int tot4 = NN * UU / 4;
    if (idx >= tot4) return;
    int i = idx >> 9;
    int j = (idx & 511) << 2;
    float4 sv = ((const float4*)S)[idx];
    float ui = u[i] - NORMC;
    float a0 = __expf(sv.x + ui + v[j + 0]);
    float a1 = __expf(sv.y + ui + v[j + 1]);
    float a2 = __expf(sv.z + ui + v[j + 2]);
    float a3 = __expf(sv.w + ui + v[j + 3]);
    ushort4 hv, lv;
    bfsplit(a0, hv.x, lv.x); bfsplit(a1, hv.y, lv.y);
    bfsplit(a2, hv.z, lv.z); bfsplit(a3, hv.w, lv.w);
    *(ushort4*)(Ah + ((size_t)idx << 2)) = hv;
    *(ushort4*)(Al + ((size_t)idx << 2)) = lv;
}

// ---------- AT_bf [UU][KP] = A^T hi/lo (zero-padded node cols) ----------
__global__ void make_AT(const float* __restrict__ S, const float* __restrict__ u,
                        const float* __restrict__ v, ushort* __restrict__ Th,
                        ushort* __restrict__ Tl) {
    __shared__ float tile[32][33];
    int bu = blockIdx.x;                         // 64 u-tiles
    int bn = blockIdx.y;                         // 126 node-tiles
    int tx = threadIdx.x;
    for (int r = threadIdx.y; r < 32; r += 8) {
        int node = bn * 32 + r;
        int uu = bu * 32 + tx;
        float val = 0.0f;
        if (node < NN)
            val = __expf(S[(size_t)node * UU + uu] + u[node] + v[uu] - NORMC);
        tile[r][tx] = val;
    }
    __syncthreads();
    for (int r = threadIdx.y; r < 32; r += 8) {
        int uu = bu * 32 + r;
        int node = bn * 32 + tx;
        ushort hi, lo; bfsplit(tile[tx][r], hi, lo);
        Th[(size_t)uu * KP + node] = hi;
        Tl[(size_t)uu * KP + node] = lo;
    }
}

// ---------- zero the node-pad columns of xT / t_nT ----------
__global__ void zero_pads(ushort* a, ushort* b, ushort* c, ushort* d) {
    int t = blockIdx.x * 256 + threadIdx.x;
    const int PADW = KP - NN;                    // 29
    const int tot = 256 * PADW;
    if (t >= tot) return;
    int row = t / PADW, col = NN + t % PADW;
    size_t idx = (size_t)row * KP + col;
    a[idx] = 0; b[idx] = 0; c[idx] = 0; d[idx] = 0;
}

// ============ split-bf16 MFMA GEMM ============
// C[M][N] = act(sum_k Aop[m][k]*Bop[n][k] + bias + res)
// Aop: [M][lda] hi/lo bf16 (k-contiguous), Bop: [N][ldb] hi/lo bf16 (k-contiguous)
// outputs: OUTF -> Cf f32 [M][N]; OUTN -> Nh/Nl bf16 [M][N]; OUTT -> Th/Tl bf16 [N][ldt]
// RES: residual from bf16 pair Rh/Rl [M][N]
template<int ACT, int BIAS, int RES, int OUTF, int OUTN, int OUTT>
__global__ __launch_bounds__(256) void gemm_bf(
        const ushort* __restrict__ Ah, const ushort* __restrict__ Al, int lda,
        const ushort* __restrict__ Bh, const ushort* __restrict__ Bl, int ldb,
        const float* __restrict__ bias,
        const ushort* __restrict__ Rh, const ushort* __restrict__ Rl,
        float* __restrict__ Cf,
        ushort* __restrict__ Nh, ushort* __restrict__ Nl,
        ushort* __restrict__ Th, ushort* __restrict__ Tl, int ldt,
        int M, int N, int K) {
    __shared__ ushort As[2][64 * 64];
    __shared__ ushort Bs[2][64 * 64];
    const int tid = threadIdx.x;
    const int bm = blockIdx.y << 6, bn = blockIdx.x << 6;
    const int lane = tid & 63;
    const int wv = tid >> 6;
    const int wm = (wv >> 1) << 5, wn = (wv & 1) << 5;
    // staging: slot = row*8 + k8chunk ; thread covers rows r0 and r0+32
    const int r0 = tid >> 3, r1 = r0 + 32;
    const int k8 = (tid & 7) << 3;               // element offset 0..56
    const int s0 = ((r0 << 6) + k8) ^ ((r0 & 7) << 3);
    const int s1 = ((r1 << 6) + k8) ^ ((r1 & 7) << 3);
    f32x4 acc[2][2] = {};
    for (int k0 = 0; k0 < K; k0 += 64) {
        uint4 vah0 = {0,0,0,0}, vah1 = {0,0,0,0}, val0 = {0,0,0,0}, val1 = {0,0,0,0};
        int gm0 = bm + r0, gm1 = bm + r1;
        if (gm0 < M) {
            size_t o = (size_t)gm0 * lda + k0 + k8;
            vah0 = *(const uint4*)(Ah + o);
            val0 = *(const uint4*)(Al + o);
        }
        if (gm1 < M) {
            size_t o = (size_t)gm1 * lda + k0 + k8;
            vah1 = *(const uint4*)(Ah + o);
            val1 = *(const uint4*)(Al + o);
        }
        size_t ob0 = (size_t)(bn + r0) * ldb + k0 + k8;
        size_t ob1 = (size_t)(bn + r1) * ldb + k0 + k8;
        uint4 vbh0 = *(const uint4*)(Bh + ob0);
        uint4 vbl0 = *(const uint4*)(Bl + ob0);
        uint4 vbh1 = *(const uint4*)(Bh + ob1);
        uint4 vbl1 = *(const uint4*)(Bl + ob1);
        __syncthreads();
        *(uint4*)&As[0][s0] = vah0;  *(uint4*)&As[0][s1] = vah1;
        *(uint4*)&As[1][s0] = val0;  *(uint4*)&As[1][s1] = val1;
        *(uint4*)&Bs[0][s0] = vbh0;  *(uint4*)&Bs[0][s1] = vbh1;
        *(uint4*)&Bs[1][s0] = vbl0;  *(uint4*)&Bs[1][s1] = vbl1;
        __syncthreads();
        #pragma unroll
        for (int ks = 0; ks < 2; ++ks) {
            int kb = (ks << 5) + ((lane >> 4) << 3);
            bf16x8 fah[2], fal[2], fbh[2], fbl[2];
            #pragma unroll
            for (int f = 0; f < 2; ++f) {
                int rr = wm + (f << 4) + (lane & 15);
                int ia = ((rr << 6) + kb) ^ ((rr & 7) << 3);
                fah[f] = *(const bf16x8*)&As[0][ia];
                fal[f] = *(const bf16x8*)&As[1][ia];
                int cc = wn + (f << 4) + (lane & 15);
                int ib = ((cc << 6) + kb) ^ ((cc & 7) << 3);
                fbh[f] = *(const bf16x8*)&Bs[0][ib];
                fbl[f] = *(const bf16x8*)&Bs[1][ib];
            }
            #pragma unroll
            for (int i = 0; i < 2; ++i)
                #pragma unroll
                for (int j = 0; j < 2; ++j) {
                    acc[i][j] = __builtin_amdgcn_mfma_f32_16x16x32_bf16(fah[i], fbh[j], acc[i][j], 0, 0, 0);
                    acc[i][j] = __builtin_amdgcn_mfma_f32_16x16x32_bf16(fah[i], fbl[j], acc[i][j], 0, 0, 0);
                    acc[i][j] = __builtin_amdgcn_mfma_f32_16x16x32_bf16(fal[i], fbh[j], acc[i][j], 0, 0, 0);
                }
        }
    }
    // epilogue: C/D layout col=lane&15, row=(lane>>4)*4+reg  [m89]
    #pragma unroll
    for (int i = 0; i < 2; ++i) {
        #pragma unroll
        for (int j = 0; j < 2; ++j) {
            int col = bn + wn + (j << 4) + (lane & 15);
            int row0 = bm + wm + (i << 4) + ((lane >> 4) << 2);
            float vals[4];
            #pragma unroll
            for (int r = 0; r < 4; ++r) {
                int row = row0 + r;
                float vv = acc[i][j][r];
                if (BIAS) vv += bias[col];
                if (RES) {
                    if (row < M)
                        vv += bf2f(Rh[(size_t)row * N + col]) + bf2f(Rl[(size_t)row * N + col]);
                }
                if (ACT == 1) vv = fmaxf(vv, 0.0f);
                if (ACT == 2) vv = tanhf(vv);
                vals[r] = vv;
                if (row < M) {
                    if (OUTF) Cf[(size_t)row * N + col] = vv;
                    if (OUTN) {
                        ushort hi, lo; bfsplit(vv, hi, lo);
                        Nh[(size_t)row * N + col] = hi;
                        Nl[(size_t)row * N + col] = lo;
                    }
                }
            }
            if (OUTT) {
                if (row0 + 3 < M) {
                    ushort4 hv, lv;
                    bfsplit(vals[0], hv.x, lv.x); bfsplit(vals[1], hv.y, lv.y);
                    bfsplit(vals[2], hv.z, lv.z); bfsplit(vals[3], hv.w, lv.w);
                    *(ushort4*)&Th[(size_t)col * ldt + row0] = hv;
                    *(ushort4*)&Tl[(size_t)col * ldt + row0] = lv;
                } else {
                    #pragma unroll
                    for (int r = 0; r < 4; ++r) if (row0 + r < M) {
                        ushort hi, lo; bfsplit(vals[r], hi, lo);
                        Th[(size_t)col * ldt + row0 + r] = hi;
                        Tl[(size_t)col * ldt + row0 + r] = lo;
                    }
                }
            }
        }
    }
}

extern "C" void kernel_launch(void* const* d_in, const int* in_sizes, int n_in,
                              void* d_out, int out_size, void* d_ws, size_t ws_size,
                              hipStream_t stream) {
    const float* dsf = (const float*)d_in[0];
    const float* unl = (const float*)d_in[1];
    const float* S   = (const float*)d_in[2];
    const float* Wb  = (const float*)d_in[3];
    const float* bb  = (const float*)d_in[4];
    const float* gcW[3] = {(const float*)d_in[5], (const float*)d_in[7], (const float*)d_in[9]};
    const float* gcb[3] = {(const float*)d_in[6], (const float*)d_in[8], (const float*)d_in[10]};
    const float* W1 = (const float*)d_in[11];
    const float* b1 = (const float*)d_in[12];
    const float* W2 = (const float*)d_in[13];
    const float* b2 = (const float*)d_in[14];
    float* out = (float*)d_out;

    // -------- workspace carve (bytes) --------
    char* p = (char*)d_ws;
    // region 0: ST f32 (sinkhorn) aliased later by AT hi/lo bf16  [33,030,144 B]
    float*  STf  = (float*)p;
    ushort* AThi = (ushort*)p;
    ushort* ATlo = AThi + (size_t)UU * KP;
    p += (size_t)UU * KP * 4;
    // A normal bf16 [NN][UU]
    ushort* Ahi = (ushort*)p; ushort* Alo = Ahi + (size_t)NN * UU; p += (size_t)NN * UU * 4;
    // feats_bf (reused as hn_bf after x-gemm)
    ushort* fh = (ushort*)p; ushort* fl = fh + (size_t)NN * 256; p += (size_t)NN * 256 * 4;
    // x_bf  (h1_bf aliases x_bf+xT region later)
    ushort* xh = (ushort*)p; ushort* xl = xh + (size_t)NN * 256; p += (size_t)NN * 256 * 4;
    // xT [256][KP]
    ushort* xTh = (ushort*)p; ushort* xTl = xTh + (size_t)256 * KP; p += (size_t)256 * KP * 4;
    // hu_bf [UU][256]
    ushort* huh = (ushort*)p; ushort* hul = huh + (size_t)UU * 256; p += (size_t)UU * 256 * 4;
    // t_uT [256][UU]
    ushort* tuTh = (ushort*)p; ushort* tuTl = tuTh + (size_t)256 * UU; p += (size_t)256 * UU * 4;
    // t_nT [256][KP]
    ushort* tnTh = (ushort*)p; ushort* tnTl = tnTh + (size_t)256 * KP; p += (size_t)256 * KP * 4;
    float* u = (float*)p; p += 16384;
    float* v = (float*)p; p += 8192;
    // weight transposes hi/lo
    ushort* WbTh = (ushort*)p; ushort* WbTl = WbTh + 256 * 256; p += 256 * 256 * 4;
    ushort* gWh[3]; ushort* gWl[3];
    for (int l = 0; l < 3; ++l) { gWh[l] = (ushort*)p; gWl[l] = gWh[l] + 256 * 256; p += 256 * 256 * 4; }
    ushort* W1Th = (ushort*)p; ushort* W1Tl = W1Th + 512 * 256; p += 512 * 256 * 4;
    ushort* W2Th = (ushort*)p; ushort* W2Tl = W2Th + 256 * 512; p += 256 * 512 * 4;
    // h1_bf aliases x_bf..xT region (both dead by head time)
    ushort* h1h = xh; ushort* h1l = h1h + (size_t)UU * 512;

    if (ws_size < (size_t)((char*)p - (char*)d_ws)) return;  // insufficient scratch (won't pass, but stay safe)

    // -------- prep --------
    concat_bf<<<dim3(1001), dim3(256), 0, stream>>>(dsf, unl, fh, fl);
    convW<<<dim3(8, 8),  dim3(32, 8), 0, stream>>>(Wb,     WbTh, WbTl, 256, 256);
    for (int l = 0; l < 3; ++l)
        convW<<<dim3(8, 8), dim3(32, 8), 0, stream>>>(gcW[l], gWh[l], gWl[l], 256, 256);
    convW<<<dim3(16, 8), dim3(32, 8), 0, stream>>>(W1,     W1Th, W1Tl, 256, 512);
    convW<<<dim3(8, 16), dim3(32, 8), 0, stream>>>(W2,     W2Th, W2Tl, 512, 256);
    zero_pads<<<dim3(29), dim3(256), 0, stream>>>(xTh, xTl, tnTh, tnTl);

    // x = relu(feats @ Wb + bb): f32 none; writes x_bf + xT
    gemm_bf<1,1,0,0,1,1><<<dim3(4, 63), dim3(256), 0, stream>>>(
        fh, fl, 256, WbTh, WbTl, 256, bb, nullptr, nullptr,
        nullptr, xh, xl, xTh, xTl, KP, NN, 256, 256);

    // -------- Sinkhorn (f32, unchanged) --------
    transpose_kernel<<<dim3(64, 126), dim3(32, 8), 0, stream>>>(S, STf);
    hipMemsetAsync(v, 0, UU * sizeof(float), stream);
    for (int it = 0; it < 20; ++it) {
        lse_rows<<<dim3(NN), dim3(256), 0, stream>>>(S,   UU, v, u, UU);
        lse_rows<<<dim3(UU), dim3(256), 0, stream>>>(STf, KP, u, v, NN);
    }

    // -------- transport plan in bf16 hi/lo (normal + transposed) --------
    make_A<<<dim3((NN * UU / 4 + 255) / 256), dim3(256), 0, stream>>>(S, u, v, Ahi, Alo);
    make_AT<<<dim3(64, 126), dim3(32, 8), 0, stream>>>(S, u, v, AThi, ATlo);  // overwrites STf

    // -------- G1: hu0 = A^T @ x --------
    gemm_bf<0,0,0,0,1,0><<<dim3(4, 32), dim3(256), 0, stream>>>(
        AThi, ATlo, KP, xTh, xTl, KP, nullptr, nullptr, nullptr,
        nullptr, huh, hul, nullptr, nullptr, 0, UU, 256, KP);

    // -------- 3 GCN layers --------
    for (int l = 0; l < 3; ++l) {
        const ushort* hnh = (l == 0) ? xh : fh;
        const ushort* hnl = (l == 0) ? xl : fl;
        if (l < 2) {
            // t_uT = (hu @ W)^T
            gemm_bf<0,0,0,0,0,1><<<dim3(4, 32), dim3(256), 0, stream>>>(
                huh, hul, 256, gWh[l], gWl[l], 256, nullptr, nullptr, nullptr,
                nullptr, nullptr, nullptr, tuTh, tuTl, UU, UU, 256, 256);
        }
        // t_nT = (hn @ W)^T
        gemm_bf<0,0,0,0,0,1><<<dim3(4, 63), dim3(256), 0, stream>>>(
            hnh, hnl, 256, gWh[l], gWl[l], 256, nullptr, nullptr, nullptr,
            nullptr, nullptr, nullptr, tnTh, tnTl, KP, NN, 256, 256);
        if (l < 2) {
            // hn_next = tanh(A @ t_u + b + hn)  -> hn_bf (fh/fl)
            gemm_bf<2,1,1,0,1,0><<<dim3(4, 63), dim3(256), 0, stream>>>(
                Ahi, Alo, UU, tuTh, tuTl, UU, gcb[l], hnh, hnl,
                nullptr, fh, fl, nullptr, nullptr, 0, NN, 256, UU);
        }
        // hu_next = tanh(A^T @ t_n + b + hu)  -> hu_bf in place
        gemm_bf<2,1,1,0,1,0><<<dim3(4, 32), dim3(256), 0, stream>>>(
            AThi, ATlo, KP, tnTh, tnTl, KP, gcb[l], huh, hul,
            nullptr, huh, hul, nullptr, nullptr, 0, UU, 256, KP);
    }

    // -------- head --------
    gemm_bf<1,1,0,0,1,0><<<dim3(8, 32), dim3(256), 0, stream>>>(
        huh, hul, 256, W1Th, W1Tl, 256, b1, nullptr, nullptr,
        nullptr, h1h, h1l, nullptr, nullptr, 0, UU, 512, 256);
    gemm_bf<0,1,0,1,0,0><<<dim3(4, 32), dim3(256), 0, stream>>>(
        h1h, h1l, 512, W2Th, W2Tl, 512, b2, nullptr, nullptr,
        out, nullptr, nullptr, nullptr, nullptr, 0, UU, 256, 512);
}

// Round 4
// 688.898 us; speedup vs baseline: 3.2226x; 1.1494x over previous
//
#include <hip/hip_runtime.h>
#include <math.h>

#define NN 4003              // label nodes
#define UU 2048              // unify nodes
#define KP 4032              // node dim padded to multiple of 64
#define N4P 4004             // NN rounded up to multiple of 4 (plane width)
#define NORMC (-8.7079796f)  // -log(4003+2048)

using bf16x8 = __attribute__((ext_vector_type(8))) short;
using f32x4  = __attribute__((ext_vector_type(4))) float;

__device__ __forceinline__ ushort f2bf(float x) {
    unsigned u = __builtin_bit_cast(unsigned, x);
    u += 0x7fff + ((u >> 16) & 1);
    return (ushort)(u >> 16);
}
__device__ __forceinline__ float bf2f(ushort h) {
    unsigned u = ((unsigned)h) << 16;
    return __builtin_bit_cast(float, u);
}
__device__ __forceinline__ void bfsplit(float x, ushort& hi, ushort& lo) {
    hi = f2bf(x);
    lo = f2bf(x - bf2f(hi));
}

// ---------- concat + f32->bf16 hi/lo: feats [NN][256] ----------
__global__ void concat_bf(const float* __restrict__ a, const float* __restrict__ b,
                          ushort* __restrict__ fh, ushort* __restrict__ fl) {
    int i = blockIdx.x * 256 + threadIdx.x;
    const int tot4 = NN * 256 / 4;
    if (i >= tot4) return;
    float4 v = (i < 256000) ? ((const float4*)a)[i] : ((const float4*)b)[i - 256000];
    ushort4 hv, lv;
    bfsplit(v.x, hv.x, lv.x); bfsplit(v.y, hv.y, lv.y);
    bfsplit(v.z, hv.z, lv.z); bfsplit(v.w, hv.w, lv.w);
    *(ushort4*)(fh + ((size_t)i << 2)) = hv;
    *(ushort4*)(fl + ((size_t)i << 2)) = lv;
}

// ---------- weight convert: W f32 [K][Nw] -> WT hi/lo bf16 [Nw][K] ----------
__global__ void convW(const float* __restrict__ W, ushort* __restrict__ Th,
                      ushort* __restrict__ Tl, int K, int Nw) {
    __shared__ float tile[32][33];
    int bx = blockIdx.x, by = blockIdx.y;
    int tx = threadIdx.x;
    for (int r = threadIdx.y; r < 32; r += 8)
        tile[r][tx] = W[(size_t)(by * 32 + r) * Nw + bx * 32 + tx];
    __syncthreads();
    for (int r = threadIdx.y; r < 32; r += 8) {
        int n = bx * 32 + r, k = by * 32 + tx;
        ushort hi, lo; bfsplit(tile[tx][r], hi, lo);
        Th[(size_t)n * K + k] = hi;
        Tl[(size_t)n * K + k] = lo;
    }
}

// ---------- transpose S[NN][UU] -> ST f32 [UU][KP] (pad cols = 0) ----------
__global__ void transpose_kernel(const float* __restrict__ in, float* __restrict__ out) {
    __shared__ float tile[32][33];
    int x = blockIdx.x * 32 + threadIdx.x;
    int y0 = blockIdx.y * 32;
    for (int r = threadIdx.y; r < 32; r += 8) {
        int y = y0 + r;
        tile[r][threadIdx.x] = (y < NN) ? in[(size_t)y * UU + x] : 0.0f;
    }
    __syncthreads();
    int oc = y0 + threadIdx.x;
    for (int r = threadIdx.y; r < 32; r += 8) {
        int orow = blockIdx.x * 32 + r;
        out[(size_t)orow * KP + oc] = tile[threadIdx.x][r];
    }
}

// ---------- u_ext pad init: exp(S + pad) must be 0 ----------
__global__ void init_uext(float* __restrict__ u_ext) {
    int i = threadIdx.x;
    if (i < KP - NN) u_ext[NN + i] = -1e30f;
}

// ------- row logsumexp: outv[r] = NORMC - lse_j(S[r][j] + addv[j]) -------
__global__ __launch_bounds__(256) void lse_rows(const float* __restrict__ S, int lda,
                                                const float* __restrict__ addv,
                                                float* __restrict__ outv, int C) {
    int r = blockIdx.x;
    const float* row = S + (size_t)r * lda;
    const float4* row4 = (const float4*)row;
    const float4* a4 = (const float4*)addv;
    float m = -INFINITY, s = 0.0f;
    int C4 = C >> 2;
    for (int j = threadIdx.x; j < C4; j += 256) {
        float4 xv = row4[j];
        float4 av = a4[j];
        float x0 = xv.x + av.x, x1 = xv.y + av.y, x2 = xv.z + av.z, x3 = xv.w + av.w;
        float mx = fmaxf(fmaxf(x0, x1), fmaxf(x2, x3));
        float nm = fmaxf(m, mx);
        s = s * __expf(m - nm) + __expf(x0 - nm) + __expf(x1 - nm)
                               + __expf(x2 - nm) + __expf(x3 - nm);
        m = nm;
    }
    int rem = C & 3;
    if ((int)threadIdx.x < rem) {
        int j = (C4 << 2) + threadIdx.x;
        float x = row[j] + addv[j];
        float nm = fmaxf(m, x);
        s = s * __expf(m - nm) + __expf(x - nm);
        m = nm;
    }
    #pragma unroll
    for (int off = 1; off < 64; off <<= 1) {
        float om = __shfl_xor(m, off, 64);
        float os = __shfl_xor(s, off, 64);
        float nm = fmaxf(m, om);
        s = s * __expf(m - nm) + os * __expf(om - nm);
        m = nm;
    }
    __shared__ float sm[4], ss[4];
    int w = threadIdx.x >> 6;
    if ((threadIdx.x & 63) == 0) { sm[w] = m; ss[w] = s; }
    __syncthreads();
    if (threadIdx.x == 0) {
        m = sm[0]; s = ss[0];
        #pragma unroll
        for (int i = 1; i < 4; ++i) {
            float om = sm[i], os = ss[i];
            float nm = fmaxf(m, om);
            s = s * __expf(m - nm) + os * __expf(om - nm);
            m = nm;
        }
        outv[r] = NORMC - (m + __logf(s));
    }
}

// ---------- on-the-fly exp row staging: 8 elems -> bf16 hi/lo packed ----------
__device__ __forceinline__ void exp_row8(const float* __restrict__ Sf,
        const float* __restrict__ rowadd, const float* __restrict__ coladd,
        int lda, int M, int gm, int kbase, uint4& hiv, uint4& lov) {
    ushort h[8], l[8];
    if (gm < M) {
        float ra = rowadd[gm] - NORMC;
        const float* rp = Sf + (size_t)gm * lda + kbase;
        float4 sa = *(const float4*)rp;
        float4 sb = *(const float4*)(rp + 4);
        float4 ca = *(const float4*)(coladd + kbase);
        float4 cb = *(const float4*)(coladd + kbase + 4);
        float vv[8] = {sa.x + ca.x, sa.y + ca.y, sa.z + ca.z, sa.w + ca.w,
                       sb.x + cb.x, sb.y + cb.y, sb.z + cb.z, sb.w + cb.w};
        #pragma unroll
        for (int e = 0; e < 8; ++e) {
            float av = __expf(vv[e] + ra);
            bfsplit(av, h[e], l[e]);
        }
    } else {
        #pragma unroll
        for (int e = 0; e < 8; ++e) { h[e] = 0; l[e] = 0; }
    }
    hiv.x = (unsigned)h[0] | ((unsigned)h[1] << 16);
    hiv.y = (unsigned)h[2] | ((unsigned)h[3] << 16);
    hiv.z = (unsigned)h[4] | ((unsigned)h[5] << 16);
    hiv.w = (unsigned)h[6] | ((unsigned)h[7] << 16);
    lov.x = (unsigned)l[0] | ((unsigned)l[1] << 16);
    lov.y = (unsigned)l[2] | ((unsigned)l[3] << 16);
    lov.z = (unsigned)l[4] | ((unsigned)l[5] << 16);
    lov.w = (unsigned)l[6] | ((unsigned)l[7] << 16);
}

// ============ split-K split-bf16 MFMA GEMM -> f32 partial planes ============
// P[z][m][n] (plane stride M*Nplane) = sum_{k in chunk z} Aop[m][k]*Bop[n][k]
// ASRC==0: Aop from bf16 hi/lo pair arrays [M][lda]
// ASRC==1: Aop = exp(Sf[m][k] + rowadd[m] + coladd[k] - NORMC), split on the fly
// Bop: bf16 hi/lo pair [Nb rows][ldb], rows >= Nb read as 0
template<int ASRC>
__global__ __launch_bounds__(256) void gemm_ks(
        const ushort* __restrict__ Ah, const ushort* __restrict__ Al,
        const float* __restrict__ Sf, const float* __restrict__ rowadd,
        const float* __restrict__ coladd, int lda,
        const ushort* __restrict__ Bh, const ushort* __restrict__ Bl, int ldb, int Nb,
        float* __restrict__ P, int M, int Nplane, int K, int Kc) {
    __shared__ ushort As[2][64 * 64];
    __shared__ ushort Bs[2][64 * 64];
    const int tid = threadIdx.x;
    const int bm = blockIdx.y << 6, bn = blockIdx.x << 6;
    const int lane = tid & 63;
    const int wv = tid >> 6;
    const int wm = (wv >> 1) << 5, wn = (wv & 1) << 5;
    const int r0 = tid >> 3, r1 = r0 + 32;
    const int k8 = (tid & 7) << 3;
    const int s0 = ((r0 << 6) + k8) ^ ((r0 & 7) << 3);
    const int s1 = ((r1 << 6) + k8) ^ ((r1 & 7) << 3);
    const int kb = blockIdx.z * Kc;
    int ke = kb + Kc; if (ke > K) ke = K;
    f32x4 acc[2][2] = {};
    for (int k0 = kb; k0 < ke; k0 += 64) {
        uint4 vah0, vah1, val0, val1;
        if (ASRC == 0) {
            vah0 = (uint4){0,0,0,0}; vah1 = vah0; val0 = vah0; val1 = vah0;
            if (bm + r0 < M) {
                size_t o = (size_t)(bm + r0) * lda + k0 + k8;
                vah0 = *(const uint4*)(Ah + o);
                val0 = *(const uint4*)(Al + o);
            }
            if (bm + r1 < M) {
                size_t o = (size_t)(bm + r1) * lda + k0 + k8;
                vah1 = *(const uint4*)(Ah + o);
                val1 = *(const uint4*)(Al + o);
            }
        } else {
            exp_row8(Sf, rowadd, coladd, lda, M, bm + r0, k0 + k8, vah0, val0);
            exp_row8(Sf, rowadd, coladd, lda, M, bm + r1, k0 + k8, vah1, val1);
        }
        uint4 vbh0 = {0,0,0,0}, vbl0 = {0,0,0,0}, vbh1 = {0,0,0,0}, vbl1 = {0,0,0,0};
        if (bn + r0 < Nb) {
            size_t o = (size_t)(bn + r0) * ldb + k0 + k8;
            vbh0 = *(const uint4*)(Bh + o);
            vbl0 = *(const uint4*)(Bl + o);
        }
        if (bn + r1 < Nb) {
            size_t o = (size_t)(bn + r1) * ldb + k0 + k8;
            vbh1 = *(const uint4*)(Bh + o);
            vbl1 = *(const uint4*)(Bl + o);
        }
        __syncthreads();
        *(uint4*)&As[0][s0] = vah0;  *(uint4*)&As[0][s1] = vah1;
        *(uint4*)&As[1][s0] = val0;  *(uint4*)&As[1][s1] = val1;
        *(uint4*)&Bs[0][s0] = vbh0;  *(uint4*)&Bs[0][s1] = vbh1;
        *(uint4*)&Bs[1][s0] = vbl0;  *(uint4*)&Bs[1][s1] = vbl1;
        __syncthreads();
        #pragma unroll
        for (int ks = 0; ks < 2; ++ks) {
            int kbq = (ks << 5) + ((lane >> 4) << 3);
            bf16x8 fah[2], fal[2], fbh[2], fbl[2];
            #pragma unroll
            for (int f = 0; f < 2; ++f) {
                int rr = wm + (f << 4) + (lane & 15);
                int ia = ((rr << 6) + kbq) ^ ((rr & 7) << 3);
                fah[f] = *(const bf16x8*)&As[0][ia];
                fal[f] = *(const bf16x8*)&As[1][ia];
                int cc = wn + (f << 4) + (lane & 15);
                int ib = ((cc << 6) + kbq) ^ ((cc & 7) << 3);
                fbh[f] = *(const bf16x8*)&Bs[0][ib];
                fbl[f] = *(const bf16x8*)&Bs[1][ib];
            }
            #pragma unroll
            for (int i = 0; i < 2; ++i)
                #pragma unroll
                for (int j = 0; j < 2; ++j) {
                    acc[i][j] = __builtin_amdgcn_mfma_f32_16x16x32_bf16(fah[i], fbh[j], acc[i][j], 0, 0, 0);
                    acc[i][j] = __builtin_amdgcn_mfma_f32_16x16x32_bf16(fah[i], fbl[j], acc[i][j], 0, 0, 0);
                    acc[i][j] = __builtin_amdgcn_mfma_f32_16x16x32_bf16(fal[i], fbh[j], acc[i][j], 0, 0, 0);
                }
        }
    }
    float* Pp = P + (size_t)blockIdx.z * ((size_t)M * Nplane);
    #pragma unroll
    for (int i = 0; i < 2; ++i) {
        #pragma unroll
        for (int j = 0; j < 2; ++j) {
            int col = bn + wn + (j << 4) + (lane & 15);
            int row0 = bm + wm + (i << 4) + ((lane >> 4) << 2);
            if (col < Nplane) {
                #pragma unroll
                for (int r = 0; r < 4; ++r)
                    if (row0 + r < M)
                        Pp[(size_t)(row0 + r) * Nplane + col] = acc[i][j][r];
            }
        }
    }
}

// ---- reduce planes + epilogue: C = act(sum_z P[z] + bias + res) ----
// BIAS: 0 none, 1 per-col, 2 per-row. OUTK: 0 f32, 1 bf16 hi/lo pair.
template<int ACT, int BIAS, int RES, int OUTK>
__global__ __launch_bounds__(256) void reduce_ks(
        const float* __restrict__ P, int zg,
        const float* __restrict__ bias,
        const ushort* __restrict__ Rh, const ushort* __restrict__ Rl,
        float* __restrict__ Cf, ushort* __restrict__ Ch, ushort* __restrict__ Cl,
        int M, int N4, int ldo) {
    int t = blockIdx.x * 256 + threadIdx.x;
    int n4w = N4 >> 2;
    int tot = M * n4w;
    if (t >= tot) return;
    int m = t / n4w;
    int n = (t - m * n4w) << 2;
    size_t pstr = (size_t)M * N4;
    const float* base = P + (size_t)m * N4 + n;
    float4 a = *(const float4*)base;
    for (int z = 1; z < zg; ++z) {
        float4 b = *(const float4*)(base + (size_t)z * pstr);
        a.x += b.x; a.y += b.y; a.z += b.z; a.w += b.w;
    }
    if (BIAS == 1) {
        float4 bv = *(const float4*)(bias + n);
        a.x += bv.x; a.y += bv.y; a.z += bv.z; a.w += bv.w;
    }
    if (BIAS == 2) {
        float s = bias[m];
        a.x += s; a.y += s; a.z += s; a.w += s;
    }
    if (RES) {
        size_t ro = (size_t)m * ldo + n;
        ushort4 rh = *(const ushort4*)(Rh + ro);
        ushort4 rl = *(const ushort4*)(Rl + ro);
        a.x += bf2f(rh.x) + bf2f(rl.x); a.y += bf2f(rh.y) + bf2f(rl.y);
        a.z += bf2f(rh.z) + bf2f(rl.z); a.w += bf2f(rh.w) + bf2f(rl.w);
    }
    if (ACT == 1) {
        a.x = fmaxf(a.x, 0.f); a.y = fmaxf(a.y, 0.f);
        a.z = fmaxf(a.z, 0.f); a.w = fmaxf(a.w, 0.f);
    }
    if (ACT == 2) {
        a.x = tanhf(a.x); a.y = tanhf(a.y); a.z = tanhf(a.z); a.w = tanhf(a.w);
    }
    size_t co = (size_t)m * ldo + n;
    if (OUTK == 0) {
        *(float4*)(Cf + co) = a;
    } else {
        ushort4 hv, lv;
        bfsplit(a.x, hv.x, lv.x); bfsplit(a.y, hv.y, lv.y);
        bfsplit(a.z, hv.z, lv.z); bfsplit(a.w, hv.w, lv.w);
        *(ushort4*)(Ch + co) = hv;
        *(ushort4*)(Cl + co) = lv;
    }
}

static inline int rgrid(int M, int N4) { return (M * (N4 >> 2) + 255) / 256; }

extern "C" void kernel_launch(void* const* d_in, const int* in_sizes, int n_in,
                              void* d_out, int out_size, void* d_ws, size_t ws_size,
                              hipStream_t stream) {
    const float* dsf = (const float*)d_in[0];
    const float* unl = (const float*)d_in[1];
    const float* S   = (const float*)d_in[2];
    const float* Wb  = (const float*)d_in[3];
    const float* bb  = (const float*)d_in[4];
    const float* gcW[3] = {(const float*)d_in[5], (const float*)d_in[7], (const float*)d_in[9]};
    const float* gcb[3] = {(const float*)d_in[6], (const float*)d_in[8], (const float*)d_in[10]};
    const float* W1 = (const float*)d_in[11];
    const float* b1 = (const float*)d_in[12];
    const float* W2 = (const float*)d_in[13];
    const float* b2 = (const float*)d_in[14];
    float* out = (float*)d_out;

    // -------- workspace carve --------
    char* p = (char*)d_ws;
    float* STf = (float*)p;  p += (size_t)UU * KP * 4;                 // 33.0 MB
    float* P   = (float*)p;  p += (size_t)4194304 * 4;                 // 16.8 MB planes
    ushort* fh = (ushort*)p; ushort* fl = fh + (size_t)NN * 256; p += (size_t)NN * 256 * 4;
    ushort* xh = (ushort*)p; ushort* xl = xh + (size_t)NN * 256; p += (size_t)NN * 256 * 4;
    ushort* xTh = (ushort*)p; ushort* xTl = xTh + (size_t)256 * KP; p += (size_t)256 * KP * 4;
    ushort* huh = (ushort*)p; ushort* hul = huh + (size_t)UU * 256; p += (size_t)UU * 256 * 4;
    ushort* tuTh = (ushort*)p; ushort* tuTl = tuTh + (size_t)256 * UU; p += (size_t)256 * UU * 4;
    ushort* tnTh = (ushort*)p; ushort* tnTl = tnTh + (size_t)256 * KP; p += (size_t)256 * KP * 4;
    float* u_ext = (float*)p; p += KP * 4;
    float* v     = (float*)p; p += UU * 4;
    ushort* WbTh = (ushort*)p; ushort* WbTl = WbTh + 256 * 256; p += 256 * 256 * 4;
    ushort* gWh[3]; ushort* gWl[3];
    for (int l = 0; l < 3; ++l) { gWh[l] = (ushort*)p; gWl[l] = gWh[l] + 256 * 256; p += 256 * 256 * 4; }
    ushort* W1Th = (ushort*)p; ushort* W1Tl = W1Th + 512 * 256; p += 512 * 256 * 4;
    ushort* W2Th = (ushort*)p; ushort* W2Tl = W2Th + 256 * 512; p += 256 * 512 * 4;
    // h1 pair aliases x + xT region (both dead by head time)
    ushort* h1h = xh; ushort* h1l = h1h + (size_t)UU * 512;
    (void)ws_size;

    // -------- prep --------
    concat_bf<<<dim3(1001), dim3(256), 0, stream>>>(dsf, unl, fh, fl);
    convW<<<dim3(8, 8),  dim3(32, 8), 0, stream>>>(Wb, WbTh, WbTl, 256, 256);
    for (int l = 0; l < 3; ++l)
        convW<<<dim3(8, 8), dim3(32, 8), 0, stream>>>(gcW[l], gWh[l], gWl[l], 256, 256);
    convW<<<dim3(16, 8), dim3(32, 8), 0, stream>>>(W1, W1Th, W1Tl, 256, 512);
    convW<<<dim3(8, 16), dim3(32, 8), 0, stream>>>(W2, W2Th, W2Tl, 512, 256);
    init_uext<<<dim3(1), dim3(64), 0, stream>>>(u_ext);
    transpose_kernel<<<dim3(64, 126), dim3(32, 8), 0, stream>>>(S, STf);
    hipMemsetAsync(v, 0, UU * sizeof(float), stream);

    // x = relu(feats @ Wb + bb)  [NN][256]
    gemm_ks<0><<<dim3(4, 63, 4), 256, 0, stream>>>(
        fh, fl, nullptr, nullptr, nullptr, 256, WbTh, WbTl, 256, 256, P, NN, 256, 256, 64);
    reduce_ks<1,1,0,1><<<rgrid(NN,256), 256, 0, stream>>>(
        P, 4, bb, nullptr, nullptr, nullptr, xh, xl, NN, 256, 256);
    // xT = x^T  [256][KP] : m=fo, n=node, bias per-row
    gemm_ks<0><<<dim3(63, 4, 4), 256, 0, stream>>>(
        WbTh, WbTl, nullptr, nullptr, nullptr, 256, fh, fl, 256, NN, P, 256, N4P, 256, 64);
    reduce_ks<1,2,0,1><<<rgrid(256,N4P), 256, 0, stream>>>(
        P, 4, bb, nullptr, nullptr, nullptr, xTh, xTl, 256, N4P, KP);

    // -------- Sinkhorn --------
    for (int it = 0; it < 20; ++it) {
        lse_rows<<<dim3(NN), dim3(256), 0, stream>>>(S,   UU, v, u_ext, UU);
        lse_rows<<<dim3(UU), dim3(256), 0, stream>>>(STf, KP, u_ext, v, NN);
    }

    // -------- G1: hu0 = A^T @ x  [UU][256], A^T on the fly from STf --------
    gemm_ks<1><<<dim3(4, 32, 8), 256, 0, stream>>>(
        nullptr, nullptr, STf, v, u_ext, KP, xTh, xTl, KP, 256, P, UU, 256, KP, 512);
    reduce_ks<0,0,0,1><<<rgrid(UU,256), 256, 0, stream>>>(
        P, 8, nullptr, nullptr, nullptr, nullptr, huh, hul, UU, 256, 256);

    // -------- 3 GCN layers --------
    for (int l = 0; l < 3; ++l) {
        const ushort* hnh = (l == 0) ? xh : fh;
        const ushort* hnl = (l == 0) ? xl : fl;
        if (l < 2) {
            // tuT[fo][u] = (hu @ W)^T
            gemm_ks<0><<<dim3(32, 4, 4), 256, 0, stream>>>(
                gWh[l], gWl[l], nullptr, nullptr, nullptr, 256, huh, hul, 256, UU, P, 256, UU, 256, 64);
            reduce_ks<0,0,0,1><<<rgrid(256,UU), 256, 0, stream>>>(
                P, 4, nullptr, nullptr, nullptr, nullptr, tuTh, tuTl, 256, UU, UU);
        }
        // tnT[fo][node] = (hn @ W)^T
        gemm_ks<0><<<dim3(63, 4, 4), 256, 0, stream>>>(
            gWh[l], gWl[l], nullptr, nullptr, nullptr, 256, hnh, hnl, 256, NN, P, 256, N4P, 256, 64);
        reduce_ks<0,0,0,1><<<rgrid(256,N4P), 256, 0, stream>>>(
            P, 4, nullptr, nullptr, nullptr, nullptr, tnTh, tnTl, 256, N4P, KP);
        if (l < 2) {
            // hn_next = tanh(A @ t_u + b + hn), A on the fly from S
            gemm_ks<1><<<dim3(4, 63, 4), 256, 0, stream>>>(
                nullptr, nullptr, S, u_ext, v, UU, tuTh, tuTl, UU, 256, P, NN, 256, UU, 512);
            reduce_ks<2,1,1,1><<<rgrid(NN,256), 256, 0, stream>>>(
                P, 4, gcb[l], hnh, hnl, nullptr, fh, fl, NN, 256, 256);
        }
        // hu_next = tanh(A^T @ t_n + b + hu), A^T on the fly from STf
        gemm_ks<1><<<dim3(4, 32, 8), 256, 0, stream>>>(
            nullptr, nullptr, STf, v, u_ext, KP, tnTh, tnTl, KP, 256, P, UU, 256, KP, 512);
        reduce_ks<2,1,1,1><<<rgrid(UU,256), 256, 0, stream>>>(
            P, 8, gcb[l], huh, hul, nullptr, huh, hul, UU, 256, 256);
    }

    // -------- head --------
    gemm_ks<0><<<dim3(8, 32, 4), 256, 0, stream>>>(
        huh, hul, nullptr, nullptr, nullptr, 256, W1Th, W1Tl, 256, 512, P, UU, 512, 256, 64);
    reduce_ks<1,1,0,1><<<rgrid(UU,512), 256, 0, stream>>>(
        P, 4, b1, nullptr, nullptr, nullptr, h1h, h1l, UU, 512, 512);
    gemm_ks<0><<<dim3(4, 32, 8), 256, 0, stream>>>(
        h1h, h1l, nullptr, nullptr, nullptr, 512, W2Th, W2Tl, 512, 256, P, UU, 256, 512, 64);
    reduce_ks<0,1,0,0><<<rgrid(UU,256), 256, 0, stream>>>(
        P, 8, b2, nullptr, nullptr, out, nullptr, nullptr, UU, 256, 256);
}